// Round 5
// baseline (357.534 us; speedup 1.0000x reference)
//
#include <hip/hip_runtime.h>
#include <math.h>

#define IN_F   50
#define HID    256
#define OUT_F  121
#define N_LAYERS 4
#define K0PAD  64

typedef __attribute__((ext_vector_type(8))) short short8;
typedef __attribute__((ext_vector_type(8))) ushort ushort8;
typedef __attribute__((ext_vector_type(4))) float f32x4;

#define GLOBAL_AS __attribute__((address_space(1)))
#define LDS_AS    __attribute__((address_space(3)))

__device__ __forceinline__ ushort f2bf(float f) {
    union { float f; unsigned u; } c; c.f = f;
    unsigned u = c.u;
    u += 0x7fffu + ((u >> 16) & 1u);
    return (ushort)(u >> 16);
}
__device__ __forceinline__ float bf2f(ushort u) {
    union { unsigned u; float f; } c; c.u = ((unsigned)u) << 16;
    return c.f;
}

// ---------------- CSR build ----------------
__global__ void hist_kernel(const int* __restrict__ dst, int* __restrict__ counts, int E) {
    int e = blockIdx.x * blockDim.x + threadIdx.x;
    if (e < E) atomicAdd(&counts[dst[e]], 1);
}

__global__ void scan_phase1(const int* __restrict__ counts, int* __restrict__ row_ptr,
                            int* __restrict__ bsum, int n) {
    __shared__ int sd[1024];
    int t = threadIdx.x;
    int i = blockIdx.x * 1024 + t;
    int v = (i < n) ? counts[i] : 0;
    sd[t] = v;
    __syncthreads();
    for (int off = 1; off < 1024; off <<= 1) {
        int tmp = (t >= off) ? sd[t - off] : 0;
        __syncthreads();
        sd[t] += tmp;
        __syncthreads();
    }
    if (i < n) row_ptr[i] = sd[t] - v;
    if (t == 1023) bsum[blockIdx.x] = sd[1023];
}

__global__ void scan_phase2(int* __restrict__ bsum, int nb) {
    __shared__ int sd[64];
    int t = threadIdx.x;
    int v = (t < nb) ? bsum[t] : 0;
    sd[t] = v;
    __syncthreads();
    for (int off = 1; off < 64; off <<= 1) {
        int tmp = (t >= off) ? sd[t - off] : 0;
        __syncthreads();
        sd[t] += tmp;
        __syncthreads();
    }
    if (t < nb) bsum[t] = sd[t] - v;
    if (t == nb - 1) bsum[nb] = sd[t];
}

__global__ void scan_phase3(int* __restrict__ row_ptr, int* __restrict__ cursor,
                            const int* __restrict__ bsum, int n, int nb) {
    int i = blockIdx.x * 1024 + threadIdx.x;
    if (i < n) {
        int v = row_ptr[i] + bsum[blockIdx.x];
        row_ptr[i] = v;
        cursor[i]  = v;
    }
    if (i == n - 1) row_ptr[n] = bsum[nb];
}

__global__ void scatter_kernel(const int* __restrict__ src, const int* __restrict__ dst,
                               const float* __restrict__ ew, int* __restrict__ cursor,
                               int* __restrict__ col, float* __restrict__ wv, int E) {
    int e = blockIdx.x * blockDim.x + threadIdx.x;
    if (e < E) {
        int d = dst[e];
        int pos = atomicAdd(&cursor[d], 1);
        col[pos] = src[e];
        wv[pos] = ew[e];
    }
}

// ---------------- conversions ----------------
__global__ void convert_x_kernel(const float* __restrict__ x, ushort* __restrict__ x_bf, int n) {
    int i = blockIdx.x * 256 + threadIdx.x;
    int nd = i >> 6, k = i & 63;
    if (nd < n) x_bf[i] = (k < IN_F) ? f2bf(x[(size_t)nd * IN_F + k]) : 0;
}

__global__ void convert_w0_kernel(const float* __restrict__ w, ushort* __restrict__ wt0) {
    int nn = blockIdx.x;
    int k = threadIdx.x;
    float v = (k < IN_F) ? w[(size_t)k * HID + nn] : 0.f;
    wt0[(size_t)nn * K0PAD + k] = f2bf(v);
}

// Wt[l][n][k] = bf16(beta*W[l][k][n] + (1-beta)*I)
__global__ void convert_w_kernel(const float* __restrict__ W, ushort* __restrict__ Wt) {
    int nn = blockIdx.x, l = blockIdx.y, k = threadIdx.x;
    float beta = logf(0.5f / (float)(l + 1) + 1.0f);
    float v = beta * W[(size_t)l * HID * HID + (size_t)k * HID + nn];
    if (k == nn) v += 1.0f - beta;
    Wt[(size_t)l * HID * HID + (size_t)nn * HID + k] = f2bf(v);
}

__global__ void convert_w1_kernel(const float* __restrict__ w1, ushort* __restrict__ Wt1) {
    int nn = blockIdx.x;
    int k = threadIdx.x;
    float v = (nn < OUT_F) ? w1[(size_t)k * OUT_F + nn] : 0.f;
    Wt1[(size_t)nn * HID + k] = f2bf(v);
}

// ---------------- lin0 MFMA: x0 = relu(x_bf @ Wt0^T + b), K=64 ----------------
__global__ __launch_bounds__(256) void lin0_mfma(
        const ushort* __restrict__ x_bf, const ushort* __restrict__ wt0,
        const float* __restrict__ b, ushort* __restrict__ x0_bf,
        ushort* __restrict__ h_bf, int M) {
    __shared__ ushort As[4][128][8];
    __shared__ ushort Bs[4][128][8];
    int tid = threadIdx.x;
    int wave = tid >> 6;
    int lane = tid & 63;
    int r16 = lane & 15, q = lane >> 4;
    int bm = blockIdx.x * 128;
    int bn = blockIdx.y * 128;
    int wm = (wave >> 1) * 64, wn = (wave & 1) * 64;

    f32x4 acc[4][4] = {};

    int srow = tid & 127;
    int koff0 = tid >> 7;
    int arow = bm + srow; if (arow >= M) arow = M - 1;
    const ushort* aptr = x_bf + (size_t)arow * K0PAD;
    const ushort* bptr = wt0 + (size_t)(bn + srow) * K0PAD;
    char* AsB = (char*)&As[0][0][0];
    char* BsB = (char*)&Bs[0][0][0];
    int woff = wave * 1024;

    const short8* As8 = (const short8*)&As[0][0][0];
    const short8* Bs8 = (const short8*)&Bs[0][0][0];

    for (int k0 = 0; k0 < K0PAD; k0 += 32) {
        __builtin_amdgcn_global_load_lds((const GLOBAL_AS void*)(aptr + k0 + koff0 * 8),
                                         (LDS_AS void*)(AsB + woff), 16, 0, 0);
        __builtin_amdgcn_global_load_lds((const GLOBAL_AS void*)(aptr + k0 + (koff0 + 2) * 8),
                                         (LDS_AS void*)(AsB + 4096 + woff), 16, 0, 0);
        __builtin_amdgcn_global_load_lds((const GLOBAL_AS void*)(bptr + k0 + koff0 * 8),
                                         (LDS_AS void*)(BsB + woff), 16, 0, 0);
        __builtin_amdgcn_global_load_lds((const GLOBAL_AS void*)(bptr + k0 + (koff0 + 2) * 8),
                                         (LDS_AS void*)(BsB + 4096 + woff), 16, 0, 0);
        __syncthreads();

        short8 av[4], bv[4];
#pragma unroll
        for (int mf = 0; mf < 4; ++mf)
            av[mf] = As8[q * 128 + wm + mf * 16 + r16];
#pragma unroll
        for (int nf = 0; nf < 4; ++nf)
            bv[nf] = Bs8[q * 128 + wn + nf * 16 + r16];
#pragma unroll
        for (int mf = 0; mf < 4; ++mf)
#pragma unroll
            for (int nf = 0; nf < 4; ++nf)
                acc[mf][nf] = __builtin_amdgcn_mfma_f32_16x16x32_bf16(av[mf], bv[nf], acc[mf][nf], 0, 0, 0);
        __syncthreads();
    }

#pragma unroll
    for (int mf = 0; mf < 4; ++mf) {
#pragma unroll
        for (int j = 0; j < 4; ++j) {
            int row = bm + wm + mf * 16 + q * 4 + j;
            if (row >= M) continue;
#pragma unroll
            for (int nf = 0; nf < 4; ++nf) {
                int c = bn + wn + nf * 16 + r16;
                size_t idx = (size_t)row * HID + c;
                ushort v = f2bf(fmaxf(acc[mf][nf][j] + b[c], 0.f));
                x0_bf[idx] = v;
                h_bf[idx]  = v;
            }
        }
    }
}

// -------- SpMM + alpha mix: 2 edges per wave (32 lanes x 16B each), pair-unrolled -----
__global__ __launch_bounds__(256) void spmm_mix_kernel(
        const int* __restrict__ row_ptr, const int* __restrict__ col,
        const float* __restrict__ wv, const ushort* __restrict__ h_bf,
        const ushort* __restrict__ x0_bf, ushort* __restrict__ s_bf, int n) {
    int node = (blockIdx.x * 256 + threadIdx.x) >> 6;
    if (node >= n) return;
    int lane = threadIdx.x & 63;
    int half = lane >> 5;               // 0: edge e, 1: edge e+1
    int l32 = lane & 31;
    int f0 = l32 * 8;                   // 8 features per lane
    int beg = row_ptr[node], end = row_ptr[node + 1];

    float a[8] = {};

#define PAIR(B)                                                                   \
    {                                                                             \
        int my_e = (B) + half;                                                    \
        int ce = my_e < end ? my_e : end - 1;                                     \
        float w = (my_e < end) ? wv[ce] : 0.f;                                    \
        int c = col[ce];                                                          \
        ushort8 v = *reinterpret_cast<const ushort8*>(&h_bf[(size_t)c * HID + f0]); \
        _Pragma("unroll")                                                         \
        for (int i = 0; i < 8; ++i) a[i] = fmaf(w, bf2f(v[i]), a[i]);             \
    }

    int base = beg;
    for (; base + 4 <= end; base += 4) {
        PAIR(base);
        PAIR(base + 2);
    }
    if (base < end) { PAIR(base); base += 2; }
    if (base < end) { PAIR(base); }
#undef PAIR

    // combine the two half-wave partials (features duplicated across halves)
#pragma unroll
    for (int i = 0; i < 8; ++i)
        a[i] += __shfl_xor(a[i], 32, 64);

    if (half == 0) {
        size_t idx = (size_t)node * HID + f0;
        ushort8 xv = *reinterpret_cast<const ushort8*>(&x0_bf[idx]);
        ushort8 r;
#pragma unroll
        for (int i = 0; i < 8; ++i)
            r[i] = f2bf(0.9f * a[i] + 0.1f * bf2f(xv[i]));
        *reinterpret_cast<ushort8*>(&s_bf[idx]) = r;
    }
}

// ---------------- MFMA layer GEMM: h_bf = relu(s @ W' + h_bf) ----------------
__global__ __launch_bounds__(256) void gemm_mfma_layer(
        const ushort* __restrict__ s_bf, const ushort* __restrict__ wt,
        ushort* __restrict__ h_bf, int M) {
    __shared__ ushort As[4][128][8];
    __shared__ ushort Bs[4][128][8];
    int tid = threadIdx.x;
    int wave = tid >> 6;
    int lane = tid & 63;
    int r16 = lane & 15, q = lane >> 4;
    int bm = blockIdx.x * 128;
    int bn = blockIdx.y * 128;
    int wm = (wave >> 1) * 64, wn = (wave & 1) * 64;

    f32x4 acc[4][4] = {};

    int srow = tid & 127;
    int koff0 = tid >> 7;
    int arow = bm + srow; if (arow >= M) arow = M - 1;
    const ushort* aptr = s_bf + (size_t)arow * HID;
    const ushort* bptr = wt + (size_t)(bn + srow) * HID;
    char* AsB = (char*)&As[0][0][0];
    char* BsB = (char*)&Bs[0][0][0];
    int woff = wave * 1024;

    const short8* As8 = (const short8*)&As[0][0][0];
    const short8* Bs8 = (const short8*)&Bs[0][0][0];

    for (int k0 = 0; k0 < HID; k0 += 32) {
        __builtin_amdgcn_global_load_lds((const GLOBAL_AS void*)(aptr + k0 + koff0 * 8),
                                         (LDS_AS void*)(AsB + woff), 16, 0, 0);
        __builtin_amdgcn_global_load_lds((const GLOBAL_AS void*)(aptr + k0 + (koff0 + 2) * 8),
                                         (LDS_AS void*)(AsB + 4096 + woff), 16, 0, 0);
        __builtin_amdgcn_global_load_lds((const GLOBAL_AS void*)(bptr + k0 + koff0 * 8),
                                         (LDS_AS void*)(BsB + woff), 16, 0, 0);
        __builtin_amdgcn_global_load_lds((const GLOBAL_AS void*)(bptr + k0 + (koff0 + 2) * 8),
                                         (LDS_AS void*)(BsB + 4096 + woff), 16, 0, 0);
        __syncthreads();

        short8 av[4], bv[4];
#pragma unroll
        for (int mf = 0; mf < 4; ++mf)
            av[mf] = As8[q * 128 + wm + mf * 16 + r16];
#pragma unroll
        for (int nf = 0; nf < 4; ++nf)
            bv[nf] = Bs8[q * 128 + wn + nf * 16 + r16];
#pragma unroll
        for (int mf = 0; mf < 4; ++mf)
#pragma unroll
            for (int nf = 0; nf < 4; ++nf)
                acc[mf][nf] = __builtin_amdgcn_mfma_f32_16x16x32_bf16(av[mf], bv[nf], acc[mf][nf], 0, 0, 0);
        __syncthreads();
    }

#pragma unroll
    for (int mf = 0; mf < 4; ++mf) {
#pragma unroll
        for (int j = 0; j < 4; ++j) {
            int row = bm + wm + mf * 16 + q * 4 + j;
            if (row >= M) continue;
#pragma unroll
            for (int nf = 0; nf < 4; ++nf) {
                int c = bn + wn + nf * 16 + r16;
                size_t idx = (size_t)row * HID + c;
                float v = fmaxf(acc[mf][nf][j] + bf2f(h_bf[idx]), 0.f);
                h_bf[idx] = f2bf(v);
            }
        }
    }
}

// ---------------- MFMA lin1: out = h @ lin1_w + b ----------------
__global__ __launch_bounds__(256) void lin1_mfma(
        const ushort* __restrict__ h_bf, const ushort* __restrict__ wt1,
        const float* __restrict__ b, float* __restrict__ out, int M) {
    __shared__ ushort As[4][128][8];
    __shared__ ushort Bs[4][128][8];
    int tid = threadIdx.x;
    int wave = tid >> 6;
    int lane = tid & 63;
    int r16 = lane & 15, q = lane >> 4;
    int bm = blockIdx.x * 128;
    int wm = (wave >> 1) * 64, wn = (wave & 1) * 64;

    f32x4 acc[4][4] = {};

    int srow = tid & 127;
    int koff0 = tid >> 7;
    int arow = bm + srow; if (arow >= M) arow = M - 1;
    const ushort* aptr = h_bf + (size_t)arow * HID;
    const ushort* bptr = wt1 + (size_t)srow * HID;
    char* AsB = (char*)&As[0][0][0];
    char* BsB = (char*)&Bs[0][0][0];
    int woff = wave * 1024;

    const short8* As8 = (const short8*)&As[0][0][0];
    const short8* Bs8 = (const short8*)&Bs[0][0][0];

    for (int k0 = 0; k0 < HID; k0 += 32) {
        __builtin_amdgcn_global_load_lds((const GLOBAL_AS void*)(aptr + k0 + koff0 * 8),
                                         (LDS_AS void*)(AsB + woff), 16, 0, 0);
        __builtin_amdgcn_global_load_lds((const GLOBAL_AS void*)(aptr + k0 + (koff0 + 2) * 8),
                                         (LDS_AS void*)(AsB + 4096 + woff), 16, 0, 0);
        __builtin_amdgcn_global_load_lds((const GLOBAL_AS void*)(bptr + k0 + koff0 * 8),
                                         (LDS_AS void*)(BsB + woff), 16, 0, 0);
        __builtin_amdgcn_global_load_lds((const GLOBAL_AS void*)(bptr + k0 + (koff0 + 2) * 8),
                                         (LDS_AS void*)(BsB + 4096 + woff), 16, 0, 0);
        __syncthreads();

        short8 av[4], bv[4];
#pragma unroll
        for (int mf = 0; mf < 4; ++mf)
            av[mf] = As8[q * 128 + wm + mf * 16 + r16];
#pragma unroll
        for (int nf = 0; nf < 4; ++nf)
            bv[nf] = Bs8[q * 128 + wn + nf * 16 + r16];
#pragma unroll
        for (int mf = 0; mf < 4; ++mf)
#pragma unroll
            for (int nf = 0; nf < 4; ++nf)
                acc[mf][nf] = __builtin_amdgcn_mfma_f32_16x16x32_bf16(av[mf], bv[nf], acc[mf][nf], 0, 0, 0);
        __syncthreads();
    }

#pragma unroll
    for (int mf = 0; mf < 4; ++mf) {
#pragma unroll
        for (int j = 0; j < 4; ++j) {
            int row = bm + wm + mf * 16 + q * 4 + j;
            if (row >= M) continue;
#pragma unroll
            for (int nf = 0; nf < 4; ++nf) {
                int c = wn + nf * 16 + r16;
                if (c < OUT_F)
                    out[(size_t)row * OUT_F + c] = acc[mf][nf][j] + b[c];
            }
        }
    }
}

extern "C" void kernel_launch(void* const* d_in, const int* in_sizes, int n_in,
                              void* d_out, int out_size, void* d_ws, size_t ws_size,
                              hipStream_t stream) {
    const float* x      = (const float*)d_in[0];
    const int*   ei     = (const int*)d_in[1];
    const float* ew     = (const float*)d_in[2];
    const float* lin0_w = (const float*)d_in[3];
    const float* lin0_b = (const float*)d_in[4];
    const float* W      = (const float*)d_in[5];
    const float* lin1_w = (const float*)d_in[6];
    const float* lin1_b = (const float*)d_in[7];
    float* out = (float*)d_out;

    int N = in_sizes[0] / IN_F;
    int E = in_sizes[2];
    const int* src = ei;
    const int* dst = ei + E;

    char* ws = (char*)d_ws;
    ushort* x0_bf   = (ushort*)ws; ws += (size_t)N * HID * 2;
    ushort* h_bf    = (ushort*)ws; ws += (size_t)N * HID * 2;
    ushort* s_bf    = (ushort*)ws; ws += (size_t)N * HID * 2;
    ushort* x_bf    = (ushort*)ws; ws += (size_t)N * K0PAD * 2;
    ushort* Wt0     = (ushort*)ws; ws += (size_t)HID * K0PAD * 2;
    ushort* Wt      = (ushort*)ws; ws += (size_t)N_LAYERS * HID * HID * 2;
    ushort* Wt1     = (ushort*)ws; ws += (size_t)128 * HID * 2;
    int*    row_ptr = (int*)ws;    ws += (size_t)(N + 1) * 4;
    int*    counts  = (int*)ws;    ws += (size_t)N * 4;
    int*    cursor  = (int*)ws;    ws += (size_t)N * 4;
    int*    bsum    = (int*)ws;    ws += (size_t)128 * 4;
    int*    col     = (int*)ws;    ws += (size_t)E * 4;
    float*  wv      = (float*)ws;  ws += (size_t)E * 4;

    int nb = (N + 1023) / 1024;

    hipMemsetAsync(counts, 0, (size_t)N * 4, stream);
    hist_kernel<<<(E + 255) / 256, 256, 0, stream>>>(dst, counts, E);
    scan_phase1<<<nb, 1024, 0, stream>>>(counts, row_ptr, bsum, N);
    scan_phase2<<<1, 64, 0, stream>>>(bsum, nb);
    scan_phase3<<<nb, 1024, 0, stream>>>(row_ptr, cursor, bsum, N, nb);
    scatter_kernel<<<(E + 255) / 256, 256, 0, stream>>>(src, dst, ew, cursor, col, wv, E);

    convert_x_kernel<<<(N * K0PAD + 255) / 256, 256, 0, stream>>>(x, x_bf, N);
    convert_w0_kernel<<<HID, K0PAD, 0, stream>>>(lin0_w, Wt0);
    convert_w_kernel<<<dim3(HID, N_LAYERS), HID, 0, stream>>>(W, Wt);
    convert_w1_kernel<<<128, HID, 0, stream>>>(lin1_w, Wt1);

    int mblocks = (N + 127) / 128;
    lin0_mfma<<<dim3(mblocks, 2), 256, 0, stream>>>(x_bf, Wt0, lin0_b, x0_bf, h_bf, N);

    for (int l = 0; l < N_LAYERS; ++l) {
        spmm_mix_kernel<<<(N + 3) / 4, 256, 0, stream>>>(row_ptr, col, wv, h_bf, x0_bf, s_bf, N);
        gemm_mfma_layer<<<dim3(mblocks, 2), 256, 0, stream>>>(
            s_bf, Wt + (size_t)l * HID * HID, h_bf, N);
    }

    lin1_mfma<<<mblocks, 256, 0, stream>>>(h_bf, Wt1, lin1_b, out, N);
}